// Round 4
// baseline (719.690 us; speedup 1.0000x reference)
//
#include <hip/hip_runtime.h>
#include <hip/hip_bf16.h>

#define N_NODES 100000
#define N_EDGES 1600000
#define D       64
#define N_RELS  200
#define LEAKY   0.01f
// fine buckets of 256 nodes
#define NBUCK      391
#define BUCK_SHIFT 8
#define BUCK_MASK  255
#define BIN_CHUNK  4096
#define NBIN       ((N_EDGES + BIN_CHUNK - 1) / BIN_CHUNK)   // 391

typedef __hip_bfloat16 bf16;

__device__ __forceinline__ float b2f(bf16 x) { return __bfloat162float(x); }
__device__ __forceinline__ bf16  f2b(float x) { return __float2bfloat16(x); }

// dtype-dispatching float load: bf==1 -> storage is bf16, else f32 (probe says f32 here)
__device__ __forceinline__ float ldf(const void* p, long i, int bf) {
    return bf ? __bfloat162float(((const bf16*)p)[i]) : ((const float*)p)[i];
}
__device__ __forceinline__ int probe_bf(const void* delta) {
    return ((const unsigned short*)delta)[0] == 0x3F80 ? 1 : 0;
}

// uniform-index lane broadcast via v_readlane (result lands in SGPR)
__device__ __forceinline__ int rl_i(int v, int l) {
    return __builtin_amdgcn_readlane(v, l);
}
__device__ __forceinline__ float rl_f(float v, int l) {
    return __int_as_float(__builtin_amdgcn_readlane(__float_as_int(v), l));
}

// K1: node proj (hWb, s_src, s_dst) + rel proj (relW f32, s_rel) + COARSE dst histogram.
// 8 nodes per wave-iteration (8 indep FMA chains); grid 781 -> exactly 2.0 iters/wave
// per phase; launch_bounds(512,8) caps VGPR at 256 -> 8 waves/SIMD resident.
__global__ __launch_bounds__(512, 8) void k_fused_proj(const void* __restrict__ h,
                                                       const void* __restrict__ wn,
                                                       const void* __restrict__ attn,
                                                       const void* __restrict__ delta,
                                                       const void* __restrict__ rel_emb,
                                                       const int* __restrict__ dst,
                                                       bf16* __restrict__ hWb,
                                                       float* __restrict__ s_src,
                                                       float* __restrict__ s_dst,
                                                       float* __restrict__ relW,
                                                       float* __restrict__ s_rel,
                                                       int* __restrict__ bcnt) {
    __shared__ int bh[NBUCK];
    const int bf = probe_bf(delta);
    const int wave = threadIdx.x >> 6;
    const int lane = threadIdx.x & 63;
    const int gw = blockIdx.x * 8 + wave;
    const int nwaves = gridDim.x * 8;
    float wreg[D];
    #pragma unroll
    for (int k = 0; k < D; k++) wreg[k] = ldf(wn, (long)k * D + lane, bf);
    const float a1 = ldf(attn, lane, bf);
    const float a2 = ldf(attn, D + lane, bf);
    // phase A: 8 nodes per iteration (N_NODES % 8 == 0)
    for (int base = gw * 8; base < N_NODES; base += nwaves * 8) {
        float hv[8], acc[8];
        #pragma unroll
        for (int j = 0; j < 8; j++) {
            hv[j] = ldf(h, (long)(base + j) * D + lane, bf);
            acc[j] = 0.f;
        }
        #pragma unroll
        for (int j = 0; j < 8; j++) {
            float p1 = hv[j] * a1, p2 = hv[j] * a2;
            #pragma unroll
            for (int off = 32; off; off >>= 1) { p1 += __shfl_xor(p1, off); p2 += __shfl_xor(p2, off); }
            if (lane == 0) { s_src[base + j] = p1; s_dst[base + j] = p2; }
        }
        #pragma unroll
        for (int k = 0; k < D; k++) {
            float w = wreg[k];
            #pragma unroll
            for (int j = 0; j < 8; j++) acc[j] += rl_f(hv[j], k) * w;
        }
        #pragma unroll
        for (int j = 0; j < 8; j++) hWb[(long)(base + j) * D + lane] = f2b(acc[j]);
    }
    // phase B: relations (200 waves; L2-hot, tiny)
    const float a3 = ldf(attn, 2 * D + lane, bf);
    for (int r = gw; r < N_RELS; r += nwaves) {
        float rv = ldf(rel_emb, (long)r * D + lane, bf);
        float p3 = rv * a3;
        #pragma unroll
        for (int off = 32; off; off >>= 1) p3 += __shfl_xor(p3, off);
        if (lane == 0) s_rel[r] = p3;
        float acc = 0.f;
        #pragma unroll
        for (int k = 0; k < D; k++) {
            acc += rl_f(rv, k) * ldf(wn, (long)(D + k) * D + lane, bf);
        }
        relW[r * D + lane] = acc;
    }
    // phase C: coarse (dst>>8) histogram, LDS-aggregated; first 256 blocks only
    // -> 256*391 = 100K global atomics.
    if (blockIdx.x < 256) {
        for (int t = threadIdx.x; t < NBUCK; t += 512) bh[t] = 0;
        __syncthreads();
        for (int t = blockIdx.x * 512 + threadIdx.x; t < N_EDGES; t += 256 * 512)
            atomicAdd(&bh[dst[t] >> BUCK_SHIFT], 1);
        __syncthreads();
        for (int t = threadIdx.x; t < NBUCK; t += 512) {
            int v = bh[t];
            if (v) atomicAdd(&bcnt[t], v);
        }
    }
}

// exclusive scan of the 391 bucket counts; primes bcursor and rowptr[N]
__global__ __launch_bounds__(512) void k_bscan(const int* __restrict__ bcnt,
                                               int* __restrict__ bbase,
                                               int* __restrict__ bcursor,
                                               int* __restrict__ rowptr) {
    __shared__ int s[512];
    const int tid = threadIdx.x;
    int v = (tid < NBUCK) ? bcnt[tid] : 0;
    s[tid] = v;
    __syncthreads();
    for (int off = 1; off < 512; off <<= 1) {
        int t = (tid >= off) ? s[tid - off] : 0;
        __syncthreads();
        s[tid] += t;
        __syncthreads();
    }
    if (tid < NBUCK) {
        int e = s[tid] - v;
        bbase[tid] = e;
        bcursor[tid] = e;
    }
    if (tid == 511) {
        bbase[NBUCK] = s[511];        // == N_EDGES
        rowptr[N_NODES] = s[511];
    }
}

// Pass B: rank edges into 391 fine buckets via LDS atomics, then scatter
// {ex, src|rel<<17} (8B) + local-dst (1B) directly into per-(block,bucket) runs.
// No LDS staging monolith: 3 barriers, ~3 KB LDS, full occupancy. Clusters of
// ~10 records per (block,bucket) keep write-line utilization acceptable; HBM
// has 6x headroom here.
__global__ __launch_bounds__(512, 8) void k_bin(const float* __restrict__ s_src,
                                                const float* __restrict__ s_dst,
                                                const float* __restrict__ s_rel,
                                                const void* __restrict__ etime,
                                                const void* __restrict__ delta,
                                                const int* __restrict__ src,
                                                const int* __restrict__ dst,
                                                const int* __restrict__ etype,
                                                int* __restrict__ bcursor,
                                                int2* __restrict__ payl,
                                                unsigned char* __restrict__ zbuf) {
    __shared__ int lh[NBUCK];
    __shared__ int gbase[NBUCK];
    const int bf = probe_bf(delta);
    const float df = ldf(delta, 0, bf);
    const int tid = threadIdx.x;
    const int base = blockIdx.x * BIN_CHUNK;
    for (int t = tid; t < NBUCK; t += 512) lh[t] = 0;
    __syncthreads();
    int2 rc[8];
    int rk[8], bk[8], zz[8];
    #pragma unroll
    for (int j = 0; j < 8; j++) {
        int e = base + j * 512 + tid;
        bk[j] = -1;
        if (e < N_EDGES) {
            int s = src[e], d = dst[e], r = etype[e];
            float scv = s_src[s] + s_dst[d] + s_rel[r];
            float lre = scv > 0.f ? scv : LEAKY * scv;
            float score = (-ldf(etime, e, bf) * df) * lre;
            rc[j].x = __float_as_int(__expf(score));
            rc[j].y = s | (r << 17);     // src < 2^17, rel < 256
            zz[j] = d & BUCK_MASK;
            int b = d >> BUCK_SHIFT;
            bk[j] = b;
            rk[j] = atomicAdd(&lh[b], 1);
        }
    }
    __syncthreads();
    for (int t = tid; t < NBUCK; t += 512) {
        int v = lh[t];
        if (v) gbase[t] = atomicAdd(&bcursor[t], v);
    }
    __syncthreads();
    #pragma unroll
    for (int j = 0; j < 8; j++) {
        if (bk[j] >= 0) {
            int pos = gbase[bk[j]] + rk[j];
            payl[pos] = rc[j];
            zbuf[pos] = (unsigned char)zz[j];
        }
    }
}

// Pass C: one workgroup per fine bucket (391 blocks, 256 nodes each).
// Pass 1 reads only the 1-byte z stream (1.6 MB total); pass 2 re-reads payl
// (fresh) and scatters 8B records within a ~32 KB window.
__global__ __launch_bounds__(512) void k_bucket(const int2* __restrict__ payl,
                                                const unsigned char* __restrict__ zbuf,
                                                const int* __restrict__ bbase,
                                                int* __restrict__ rowptr,
                                                int2* __restrict__ sorted) {
    __shared__ int fh[256];
    __shared__ int fc[256];
    __shared__ int sc[256];
    const int tid = threadIdx.x;
    const int b = blockIdx.x;
    const int n0 = b << BUCK_SHIFT;
    const int s0 = bbase[b], s1 = bbase[b + 1];
    if (tid < 256) { fh[tid] = 0; fc[tid] = 0; }
    __syncthreads();
    for (int i = s0 + tid; i < s1; i += 512) atomicAdd(&fh[zbuf[i]], 1);
    __syncthreads();
    if (tid < 256) sc[tid] = fh[tid];
    __syncthreads();
    for (int off = 1; off < 256; off <<= 1) {
        int t = 0;
        if (tid < 256 && tid >= off) t = sc[tid - off];
        __syncthreads();
        if (tid < 256) sc[tid] += t;
        __syncthreads();
    }
    if (tid < 256) {
        int excl = sc[tid] - fh[tid];
        fh[tid] = excl;                               // fh now = exclusive offsets
        if (n0 + tid < N_NODES) rowptr[n0 + tid] = s0 + excl;
    }
    __syncthreads();
    for (int i = s0 + tid; i < s1; i += 512) {
        int2 r = payl[i];
        int z = zbuf[i];
        int p = s0 + fh[z] + atomicAdd(&fc[z], 1);
        sorted[p] = r;
    }
}

// Dense loop-term: L[i] = h[i] @ loopW for ALL nodes — same no-branch structure
// as proj phase A. deg==0 nodes (P = e^-16) corrected in k_aggregate's cold branch.
__global__ __launch_bounds__(512, 8) void k_loop(const void* __restrict__ h,
                                                 const void* __restrict__ loopW,
                                                 const void* __restrict__ delta,
                                                 float* __restrict__ L) {
    const int bf = probe_bf(delta);
    const int wave = threadIdx.x >> 6;
    const int lane = threadIdx.x & 63;
    const int gw = blockIdx.x * 8 + wave;
    const int nwaves = gridDim.x * 8;
    float wreg[D];
    #pragma unroll
    for (int k = 0; k < D; k++) wreg[k] = ldf(loopW, (long)k * D + lane, bf);
    for (int base = gw * 4; base < N_NODES; base += nwaves * 4) {
        float hv[4], acc[4];
        #pragma unroll
        for (int j = 0; j < 4; j++) {
            hv[j] = ldf(h, (long)(base + j) * D + lane, bf);
            acc[j] = 0.f;
        }
        #pragma unroll
        for (int k = 0; k < D; k++) {
            float w = wreg[k];
            acc[0] += rl_f(hv[0], k) * w;
            acc[1] += rl_f(hv[1], k) * w;
            acc[2] += rl_f(hv[2], k) * w;
            acc[3] += rl_f(hv[3], k) * w;
        }
        #pragma unroll
        for (int j = 0; j < 4; j++) L[(long)(base + j) * D + lane] = acc[j];
    }
}

// wave per node, 4-edge-parallel gather: lane groups (grp=lane>>4) each own one edge
// of a 4-edge step, 4 channels per lane (sub=lane&15). No LDS; loop term from L.
__global__ __launch_bounds__(512, 8) void k_aggregate(const int* __restrict__ rowptr,
                                                      const int2* __restrict__ sorted,
                                                      const bf16* __restrict__ hWb,
                                                      const float* __restrict__ relW,
                                                      const void* __restrict__ h,
                                                      const void* __restrict__ evolveW,
                                                      const float* __restrict__ L,
                                                      const void* __restrict__ delta,
                                                      float* __restrict__ out) {
    const int bf = probe_bf(delta);
    const int wave = threadIdx.x >> 6;
    const int lane = threadIdx.x & 63;
    const int grp  = lane >> 4;
    const int sub  = lane & 15;
    const unsigned sub8  = (unsigned)sub << 3;
    const unsigned sub16 = (unsigned)sub << 4;
    const int wstride = gridDim.x * 8;
    for (int i = blockIdx.x * 8 + wave; i < N_NODES; i += wstride) {
        const int s0 = rowptr[i], e1 = rowptr[i + 1];
        if (e1 > s0) {
            float ax = 0.f, ay = 0.f, az = 0.f, aw = 0.f;
            float ls = 0.f;
            for (int c = s0; c < e1; c += 64) {
                int n = e1 - c; n = n > 64 ? 64 : n;
                float exl = 0.f; int pk = 0;
                if (lane < n) {
                    int2 rec = sorted[c + lane];
                    exl = __int_as_float(rec.x);
                    pk = rec.y;
                }
                float cs = exl;
                #pragma unroll
                for (int off = 32; off; off >>= 1) cs += __shfl_xor(cs, off);
                ls += cs;
                // group grp handles edge j+grp; lanes beyond n carry w=0 -> no tail code
                #pragma unroll 2
                for (int j = 0; j < n; j += 4) {
                    float w = __shfl(exl, j + grp);
                    int   p = __shfl(pk,  j + grp);
                    unsigned hoff = ((unsigned)(p & 0x1FFFF) << 7) + sub8;
                    unsigned roff = ((unsigned)(p >> 17) << 8) + sub16;
                    uint2  hw = *(const uint2*) ((const char*)hWb  + hoff);
                    float4 rw = *(const float4*)((const char*)relW + roff);
                    float f0 = __uint_as_float(hw.x << 16);
                    float f1 = __uint_as_float(hw.x & 0xFFFF0000u);
                    float f2 = __uint_as_float(hw.y << 16);
                    float f3 = __uint_as_float(hw.y & 0xFFFF0000u);
                    ax += w * (f0 + rw.x);
                    ay += w * (f1 + rw.y);
                    az += w * (f2 + rw.z);
                    aw += w * (f3 + rw.w);
                }
            }
            // fold the 4 group-partials (butterfly over lane bits 4,5)
            ax += __shfl_xor(ax, 16); ax += __shfl_xor(ax, 32);
            ay += __shfl_xor(ay, 16); ay += __shfl_xor(ay, 32);
            az += __shfl_xor(az, 16); az += __shfl_xor(az, 32);
            aw += __shfl_xor(aw, 16); aw += __shfl_xor(aw, 32);
            if (grp == 0) {
                const float inv = 1.f / ls;      // ls > 0: every stored ex = exp(finite) > 0
                const float4 l4 = *(const float4*)(L + (long)i * D + sub * 4);
                float4 r;
                r.x = ax * inv + l4.x;
                r.y = ay * inv + l4.y;
                r.z = az * inv + l4.z;
                r.w = aw * inv + l4.w;
                *(float4*)(out + (long)i * D + sub * 4) = r;
            }
        } else {
            // cold: deg==0 has P = e^-16 (~0.01 nodes expected). Recompute
            // out = h + h @ evolveW with a small readlane loop; evolveW is L2-hot.
            float hv = ldf(h, (long)i * D + lane, bf);
            float acc = hv;
            for (int k = 0; k < D; k++)
                acc += rl_f(hv, k) * ldf(evolveW, (long)k * D + lane, bf);
            out[(long)i * D + lane] = acc;
        }
    }
}

// safe diagnostic fallback
__global__ __launch_bounds__(256) void k_fallback(float* __restrict__ out) {
    int t = blockIdx.x * blockDim.x + threadIdx.x;
    if (t < N_NODES * D) out[t] = 0.f;
}

extern "C" void kernel_launch(void* const* d_in, const int* in_sizes, int n_in,
                              void* d_out, int out_size, void* d_ws, size_t ws_size,
                              hipStream_t stream) {
    const void* h       = d_in[0];
    const void* rel_emb = d_in[1];
    const void* wn      = d_in[2];
    const void* attn    = d_in[3];
    const void* delta   = d_in[4];
    const void* loopW   = d_in[5];
    const void* evolveW = d_in[6];
    const void* etime   = d_in[7];
    const int*  src     = (const int*)d_in[8];
    const int*  dst     = (const int*)d_in[9];
    const int*  etype   = (const int*)d_in[10];
    float* out = (float*)d_out;

    char* ws = (char*)d_ws;
    size_t off = 0;
    auto alloc = [&](size_t bytes) -> void* {
        off = (off + 255) & ~(size_t)255;
        void* p = ws + off;
        off += bytes;
        return p;
    };
    // region A (25.6 MB): payl (12.8) + zbuf (1.6) during the sort; L (25.6)
    // overlays it after k_bucket finishes reading (same-stream ordering).
    char*  regionA = (char*) alloc((size_t)N_NODES * D * 4);   // 25.6 MB
    int2*  sorted  = (int2*) alloc((size_t)N_EDGES * 8);       // 12.8 MB
    bf16*  hWb     = (bf16*) alloc((size_t)N_NODES * D * 2);   // 12.8 MB
    float* relW    = (float*)alloc((size_t)N_RELS * D * 4);    // 51.2 KB
    float* s_src   = (float*)alloc((size_t)N_NODES * 4);       //  0.4 MB
    float* s_dst   = (float*)alloc((size_t)N_NODES * 4);       //  0.4 MB
    float* s_rel   = (float*)alloc((size_t)N_RELS * 4);        //  0.8 KB
    int*   rowptr  = (int*)  alloc((size_t)(N_NODES + 1) * 4); //  0.4 MB
    int*   bcnt    = (int*)  alloc((size_t)NBUCK * 4);
    int*   bbase   = (int*)  alloc((size_t)(NBUCK + 1) * 4);
    int*   bcursor = (int*)  alloc((size_t)NBUCK * 4);

    int2* payl = (int2*)regionA;                               // 12.8 MB
    unsigned char* zbuf = (unsigned char*)(regionA + (size_t)N_EDGES * 8);  // 1.6 MB
    float* L = (float*)regionA;                                // 25.6 MB (after bucket)

    if (ws_size < off) {
        k_fallback<<<(N_NODES * D + 255) / 256, 256, 0, stream>>>(out);
        return;
    }

    hipMemsetAsync(bcnt, 0, (size_t)NBUCK * 4, stream);
    k_fused_proj<<<781, 512, 0, stream>>>(h, wn, attn, delta, rel_emb, dst,
                                          hWb, s_src, s_dst, relW, s_rel, bcnt);
    k_bscan<<<1, 512, 0, stream>>>(bcnt, bbase, bcursor, rowptr);
    k_bin<<<NBIN, 512, 0, stream>>>(s_src, s_dst, s_rel, etime, delta,
                                    src, dst, etype, bcursor, payl, zbuf);
    k_bucket<<<NBUCK, 512, 0, stream>>>(payl, zbuf, bbase, rowptr, sorted);
    k_loop<<<781, 512, 0, stream>>>(h, loopW, delta, L);
    k_aggregate<<<2048, 512, 0, stream>>>(rowptr, sorted, hWb, relW, h, evolveW, L, delta, out);
}

// Round 7
// 311.830 us; speedup vs baseline: 2.3080x; 2.3080x over previous
//
#include <hip/hip_runtime.h>
#include <hip/hip_bf16.h>

#define N_NODES 100000
#define N_EDGES 1600000
#define D       64
#define N_RELS  200
#define LEAKY   0.01f
// fine buckets of 256 nodes
#define NBUCK      391
#define BUCK_SHIFT 8
#define BUCK_MASK  255
#define BIN_CHUNK  4096
#define NBIN       ((N_EDGES + BIN_CHUNK - 1) / BIN_CHUNK)   // 391

typedef __hip_bfloat16 bf16;

__device__ __forceinline__ float b2f(bf16 x) { return __bfloat162float(x); }
__device__ __forceinline__ bf16  f2b(float x) { return __float2bfloat16(x); }

// dtype-dispatching float load: bf==1 -> storage is bf16, else f32 (probe says f32 here)
__device__ __forceinline__ float ldf(const void* p, long i, int bf) {
    return bf ? __bfloat162float(((const bf16*)p)[i]) : ((const float*)p)[i];
}
__device__ __forceinline__ int probe_bf(const void* delta) {
    return ((const unsigned short*)delta)[0] == 0x3F80 ? 1 : 0;
}

// uniform-index lane broadcast via v_readlane (result lands in SGPR)
__device__ __forceinline__ int rl_i(int v, int l) {
    return __builtin_amdgcn_readlane(v, l);
}
__device__ __forceinline__ float rl_f(float v, int l) {
    return __int_as_float(__builtin_amdgcn_readlane(__float_as_int(v), l));
}

// K1: node proj (hWb, s_src, s_dst) + rel proj (relW f32, s_rel) + COARSE dst histogram.
// EXACT round-3 structure (measured 78 us, no spill): 4 nodes/iter, (512,4) -> 128-VGPR
// cap fits wreg[64]+hv[4]+acc[4]. NOTE: (512,8) caps at 64 VGPR and spills wreg -> 289 us.
__global__ __launch_bounds__(512, 4) void k_fused_proj(const void* __restrict__ h,
                                                       const void* __restrict__ wn,
                                                       const void* __restrict__ attn,
                                                       const void* __restrict__ delta,
                                                       const void* __restrict__ rel_emb,
                                                       const int* __restrict__ dst,
                                                       bf16* __restrict__ hWb,
                                                       float* __restrict__ s_src,
                                                       float* __restrict__ s_dst,
                                                       float* __restrict__ relW,
                                                       float* __restrict__ s_rel,
                                                       int* __restrict__ bcnt) {
    __shared__ int bh[NBUCK];
    const int bf = probe_bf(delta);
    const int wave = threadIdx.x >> 6;
    const int lane = threadIdx.x & 63;
    const int gw = blockIdx.x * 8 + wave;
    const int nwaves = gridDim.x * 8;
    float wreg[D];
    #pragma unroll
    for (int k = 0; k < D; k++) wreg[k] = ldf(wn, (long)k * D + lane, bf);
    const float a1 = ldf(attn, lane, bf);
    const float a2 = ldf(attn, D + lane, bf);
    for (int base = gw * 4; base < N_NODES; base += nwaves * 4) {
        float hv[4], acc[4];
        #pragma unroll
        for (int j = 0; j < 4; j++) {
            hv[j] = ldf(h, (long)(base + j) * D + lane, bf);
            acc[j] = 0.f;
        }
        #pragma unroll
        for (int j = 0; j < 4; j++) {
            float p1 = hv[j] * a1, p2 = hv[j] * a2;
            #pragma unroll
            for (int off = 32; off; off >>= 1) { p1 += __shfl_xor(p1, off); p2 += __shfl_xor(p2, off); }
            if (lane == 0) { s_src[base + j] = p1; s_dst[base + j] = p2; }
        }
        #pragma unroll
        for (int k = 0; k < D; k++) {
            float w = wreg[k];
            acc[0] += rl_f(hv[0], k) * w;
            acc[1] += rl_f(hv[1], k) * w;
            acc[2] += rl_f(hv[2], k) * w;
            acc[3] += rl_f(hv[3], k) * w;
        }
        #pragma unroll
        for (int j = 0; j < 4; j++) hWb[(long)(base + j) * D + lane] = f2b(acc[j]);
    }
    const float a3 = ldf(attn, 2 * D + lane, bf);
    for (int r = gw; r < N_RELS; r += nwaves) {
        float rv = ldf(rel_emb, (long)r * D + lane, bf);
        float p3 = rv * a3;
        #pragma unroll
        for (int off = 32; off; off >>= 1) p3 += __shfl_xor(p3, off);
        if (lane == 0) s_rel[r] = p3;
        float acc = 0.f;
        #pragma unroll
        for (int k = 0; k < D; k++) {
            acc += rl_f(rv, k) * ldf(wn, (long)(D + k) * D + lane, bf);
        }
        relW[r * D + lane] = acc;
    }
    // phase C: coarse (dst>>8) histogram, LDS-aggregated
    for (int t = threadIdx.x; t < NBUCK; t += 512) bh[t] = 0;
    __syncthreads();
    for (int t = blockIdx.x * 512 + threadIdx.x; t < N_EDGES; t += gridDim.x * 512)
        atomicAdd(&bh[dst[t] >> BUCK_SHIFT], 1);
    __syncthreads();
    for (int t = threadIdx.x; t < NBUCK; t += 512) {
        int v = bh[t];
        if (v) atomicAdd(&bcnt[t], v);
    }
}

// exclusive scan of the 391 bucket counts; primes bcursor and rowptr[N]
__global__ __launch_bounds__(512) void k_bscan(const int* __restrict__ bcnt,
                                               int* __restrict__ bbase,
                                               int* __restrict__ bcursor,
                                               int* __restrict__ rowptr) {
    __shared__ int s[512];
    const int tid = threadIdx.x;
    int v = (tid < NBUCK) ? bcnt[tid] : 0;
    s[tid] = v;
    __syncthreads();
    for (int off = 1; off < 512; off <<= 1) {
        int t = (tid >= off) ? s[tid - off] : 0;
        __syncthreads();
        s[tid] += t;
        __syncthreads();
    }
    if (tid < NBUCK) {
        int e = s[tid] - v;
        bbase[tid] = e;
        bcursor[tid] = e;
    }
    if (tid == 511) {
        bbase[NBUCK] = s[511];        // == N_EDGES
        rowptr[N_NODES] = s[511];
    }
}

// Pass B: rank edges into 391 fine buckets via LDS atomics, then scatter
// {ex, src|rel<<17} (8B) + local-dst (1B) directly into per-(block,bucket) runs
// (avg run ~10 records = 84B contiguous). 3 barriers, ~3 KB LDS.
// (512,4): grid 391 means <=2 blocks/CU anyway; 128-VGPR cap avoids spill of rc[8]/rk/bk/zz.
__global__ __launch_bounds__(512, 4) void k_bin(const float* __restrict__ s_src,
                                                const float* __restrict__ s_dst,
                                                const float* __restrict__ s_rel,
                                                const void* __restrict__ etime,
                                                const void* __restrict__ delta,
                                                const int* __restrict__ src,
                                                const int* __restrict__ dst,
                                                const int* __restrict__ etype,
                                                int* __restrict__ bcursor,
                                                int2* __restrict__ payl,
                                                unsigned char* __restrict__ zbuf) {
    __shared__ int lh[NBUCK];
    __shared__ int gbase[NBUCK];
    const int bf = probe_bf(delta);
    const float df = ldf(delta, 0, bf);
    const int tid = threadIdx.x;
    const int base = blockIdx.x * BIN_CHUNK;
    for (int t = tid; t < NBUCK; t += 512) lh[t] = 0;
    __syncthreads();
    int2 rc[8];
    int rk[8], bk[8], zz[8];
    #pragma unroll
    for (int j = 0; j < 8; j++) {
        int e = base + j * 512 + tid;
        bk[j] = -1;
        if (e < N_EDGES) {
            int s = src[e], d = dst[e], r = etype[e];
            float scv = s_src[s] + s_dst[d] + s_rel[r];
            float lre = scv > 0.f ? scv : LEAKY * scv;
            float score = (-ldf(etime, e, bf) * df) * lre;
            rc[j].x = __float_as_int(__expf(score));
            rc[j].y = s | (r << 17);     // src < 2^17, rel < 256
            zz[j] = d & BUCK_MASK;
            int b = d >> BUCK_SHIFT;
            bk[j] = b;
            rk[j] = atomicAdd(&lh[b], 1);
        }
    }
    __syncthreads();
    for (int t = tid; t < NBUCK; t += 512) {
        int v = lh[t];
        if (v) gbase[t] = atomicAdd(&bcursor[t], v);
    }
    __syncthreads();
    #pragma unroll
    for (int j = 0; j < 8; j++) {
        if (bk[j] >= 0) {
            int pos = gbase[bk[j]] + rk[j];
            payl[pos] = rc[j];
            zbuf[pos] = (unsigned char)zz[j];
        }
    }
}

// Pass C: one workgroup per fine bucket (391 blocks, 256 nodes each).
// Pass 1 reads only the 1-byte z stream (1.6 MB total); pass 2 re-reads payl
// and scatters 8B records within a ~32 KB window.
__global__ __launch_bounds__(512) void k_bucket(const int2* __restrict__ payl,
                                                const unsigned char* __restrict__ zbuf,
                                                const int* __restrict__ bbase,
                                                int* __restrict__ rowptr,
                                                int2* __restrict__ sorted) {
    __shared__ int fh[256];
    __shared__ int fc[256];
    __shared__ int sc[256];
    const int tid = threadIdx.x;
    const int b = blockIdx.x;
    const int n0 = b << BUCK_SHIFT;
    const int s0 = bbase[b], s1 = bbase[b + 1];
    if (tid < 256) { fh[tid] = 0; fc[tid] = 0; }
    __syncthreads();
    for (int i = s0 + tid; i < s1; i += 512) atomicAdd(&fh[zbuf[i]], 1);
    __syncthreads();
    if (tid < 256) sc[tid] = fh[tid];
    __syncthreads();
    for (int off = 1; off < 256; off <<= 1) {
        int t = 0;
        if (tid < 256 && tid >= off) t = sc[tid - off];
        __syncthreads();
        if (tid < 256) sc[tid] += t;
        __syncthreads();
    }
    if (tid < 256) {
        int excl = sc[tid] - fh[tid];
        fh[tid] = excl;                               // fh now = exclusive offsets
        if (n0 + tid < N_NODES) rowptr[n0 + tid] = s0 + excl;
    }
    __syncthreads();
    for (int i = s0 + tid; i < s1; i += 512) {
        int2 r = payl[i];
        int z = zbuf[i];
        int p = s0 + fh[z] + atomicAdd(&fc[z], 1);
        sorted[p] = r;
    }
}

// Dense loop-term: L[i] = h[i] @ loopW for ALL nodes — EXACT round-3 structure
// ((512,4): 128-VGPR cap fits wreg[64]; (512,8) spills). deg==0 nodes (P=e^-16)
// corrected in k_aggregate's cold branch.
__global__ __launch_bounds__(512, 4) void k_loop(const void* __restrict__ h,
                                                 const void* __restrict__ loopW,
                                                 const void* __restrict__ delta,
                                                 float* __restrict__ L) {
    const int bf = probe_bf(delta);
    const int wave = threadIdx.x >> 6;
    const int lane = threadIdx.x & 63;
    const int gw = blockIdx.x * 8 + wave;
    const int nwaves = gridDim.x * 8;
    float wreg[D];
    #pragma unroll
    for (int k = 0; k < D; k++) wreg[k] = ldf(loopW, (long)k * D + lane, bf);
    for (int base = gw * 4; base < N_NODES; base += nwaves * 4) {
        float hv[4], acc[4];
        #pragma unroll
        for (int j = 0; j < 4; j++) {
            hv[j] = ldf(h, (long)(base + j) * D + lane, bf);
            acc[j] = 0.f;
        }
        #pragma unroll
        for (int k = 0; k < D; k++) {
            float w = wreg[k];
            acc[0] += rl_f(hv[0], k) * w;
            acc[1] += rl_f(hv[1], k) * w;
            acc[2] += rl_f(hv[2], k) * w;
            acc[3] += rl_f(hv[3], k) * w;
        }
        #pragma unroll
        for (int j = 0; j < 4; j++) L[(long)(base + j) * D + lane] = acc[j];
    }
}

// wave per node, 4-edge-parallel gather: lane groups (grp=lane>>4) each own one edge
// of a 4-edge step, 4 channels per lane (sub=lane&15). No LDS; loop term from L.
// VGPR ~24 -> safe at (512,8).
__global__ __launch_bounds__(512, 8) void k_aggregate(const int* __restrict__ rowptr,
                                                      const int2* __restrict__ sorted,
                                                      const bf16* __restrict__ hWb,
                                                      const float* __restrict__ relW,
                                                      const void* __restrict__ h,
                                                      const void* __restrict__ evolveW,
                                                      const float* __restrict__ L,
                                                      const void* __restrict__ delta,
                                                      float* __restrict__ out) {
    const int bf = probe_bf(delta);
    const int wave = threadIdx.x >> 6;
    const int lane = threadIdx.x & 63;
    const int grp  = lane >> 4;
    const int sub  = lane & 15;
    const unsigned sub8  = (unsigned)sub << 3;
    const unsigned sub16 = (unsigned)sub << 4;
    const int wstride = gridDim.x * 8;
    for (int i = blockIdx.x * 8 + wave; i < N_NODES; i += wstride) {
        const int s0 = rowptr[i], e1 = rowptr[i + 1];
        if (e1 > s0) {
            float ax = 0.f, ay = 0.f, az = 0.f, aw = 0.f;
            float ls = 0.f;
            for (int c = s0; c < e1; c += 64) {
                int n = e1 - c; n = n > 64 ? 64 : n;
                float exl = 0.f; int pk = 0;
                if (lane < n) {
                    int2 rec = sorted[c + lane];
                    exl = __int_as_float(rec.x);
                    pk = rec.y;
                }
                float cs = exl;
                #pragma unroll
                for (int off = 32; off; off >>= 1) cs += __shfl_xor(cs, off);
                ls += cs;
                // group grp handles edge j+grp; lanes beyond n carry w=0 -> no tail code
                #pragma unroll 2
                for (int j = 0; j < n; j += 4) {
                    float w = __shfl(exl, j + grp);
                    int   p = __shfl(pk,  j + grp);
                    unsigned hoff = ((unsigned)(p & 0x1FFFF) << 7) + sub8;
                    unsigned roff = ((unsigned)(p >> 17) << 8) + sub16;
                    uint2  hw = *(const uint2*) ((const char*)hWb  + hoff);
                    float4 rw = *(const float4*)((const char*)relW + roff);
                    float f0 = __uint_as_float(hw.x << 16);
                    float f1 = __uint_as_float(hw.x & 0xFFFF0000u);
                    float f2 = __uint_as_float(hw.y << 16);
                    float f3 = __uint_as_float(hw.y & 0xFFFF0000u);
                    ax += w * (f0 + rw.x);
                    ay += w * (f1 + rw.y);
                    az += w * (f2 + rw.z);
                    aw += w * (f3 + rw.w);
                }
            }
            // fold the 4 group-partials (butterfly over lane bits 4,5)
            ax += __shfl_xor(ax, 16); ax += __shfl_xor(ax, 32);
            ay += __shfl_xor(ay, 16); ay += __shfl_xor(ay, 32);
            az += __shfl_xor(az, 16); az += __shfl_xor(az, 32);
            aw += __shfl_xor(aw, 16); aw += __shfl_xor(aw, 32);
            if (grp == 0) {
                const float inv = 1.f / ls;      // ls > 0: every stored ex = exp(finite) > 0
                const float4 l4 = *(const float4*)(L + (long)i * D + sub * 4);
                float4 r;
                r.x = ax * inv + l4.x;
                r.y = ay * inv + l4.y;
                r.z = az * inv + l4.z;
                r.w = aw * inv + l4.w;
                *(float4*)(out + (long)i * D + sub * 4) = r;
            }
        } else {
            // cold: deg==0 has P = e^-16 (~0.01 nodes expected). Recompute
            // out = h + h @ evolveW with a small readlane loop; evolveW is L2-hot.
            float hv = ldf(h, (long)i * D + lane, bf);
            float acc = hv;
            for (int k = 0; k < D; k++)
                acc += rl_f(hv, k) * ldf(evolveW, (long)k * D + lane, bf);
            out[(long)i * D + lane] = acc;
        }
    }
}

// safe diagnostic fallback
__global__ __launch_bounds__(256) void k_fallback(float* __restrict__ out) {
    int t = blockIdx.x * blockDim.x + threadIdx.x;
    if (t < N_NODES * D) out[t] = 0.f;
}

extern "C" void kernel_launch(void* const* d_in, const int* in_sizes, int n_in,
                              void* d_out, int out_size, void* d_ws, size_t ws_size,
                              hipStream_t stream) {
    const void* h       = d_in[0];
    const void* rel_emb = d_in[1];
    const void* wn      = d_in[2];
    const void* attn    = d_in[3];
    const void* delta   = d_in[4];
    const void* loopW   = d_in[5];
    const void* evolveW = d_in[6];
    const void* etime   = d_in[7];
    const int*  src     = (const int*)d_in[8];
    const int*  dst     = (const int*)d_in[9];
    const int*  etype   = (const int*)d_in[10];
    float* out = (float*)d_out;

    char* ws = (char*)d_ws;
    size_t off = 0;
    auto alloc = [&](size_t bytes) -> void* {
        off = (off + 255) & ~(size_t)255;
        void* p = ws + off;
        off += bytes;
        return p;
    };
    // region A (25.6 MB): payl (12.8) + zbuf (1.6) during the sort; L (25.6)
    // overlays it after k_bucket finishes reading (same-stream ordering).
    char*  regionA = (char*) alloc((size_t)N_NODES * D * 4);   // 25.6 MB
    int2*  sorted  = (int2*) alloc((size_t)N_EDGES * 8);       // 12.8 MB
    bf16*  hWb     = (bf16*) alloc((size_t)N_NODES * D * 2);   // 12.8 MB
    float* relW    = (float*)alloc((size_t)N_RELS * D * 4);    // 51.2 KB
    float* s_src   = (float*)alloc((size_t)N_NODES * 4);       //  0.4 MB
    float* s_dst   = (float*)alloc((size_t)N_NODES * 4);       //  0.4 MB
    float* s_rel   = (float*)alloc((size_t)N_RELS * 4);        //  0.8 KB
    int*   rowptr  = (int*)  alloc((size_t)(N_NODES + 1) * 4); //  0.4 MB
    int*   bcnt    = (int*)  alloc((size_t)NBUCK * 4);
    int*   bbase   = (int*)  alloc((size_t)(NBUCK + 1) * 4);
    int*   bcursor = (int*)  alloc((size_t)NBUCK * 4);

    int2* payl = (int2*)regionA;                               // 12.8 MB
    unsigned char* zbuf = (unsigned char*)(regionA + (size_t)N_EDGES * 8);  // 1.6 MB
    float* L = (float*)regionA;                                // 25.6 MB (after bucket)

    if (ws_size < off) {
        k_fallback<<<(N_NODES * D + 255) / 256, 256, 0, stream>>>(out);
        return;
    }

    hipMemsetAsync(bcnt, 0, (size_t)NBUCK * 4, stream);
    k_fused_proj<<<1024, 512, 0, stream>>>(h, wn, attn, delta, rel_emb, dst,
                                           hWb, s_src, s_dst, relW, s_rel, bcnt);
    k_bscan<<<1, 512, 0, stream>>>(bcnt, bbase, bcursor, rowptr);
    k_bin<<<NBIN, 512, 0, stream>>>(s_src, s_dst, s_rel, etime, delta,
                                    src, dst, etype, bcursor, payl, zbuf);
    k_bucket<<<NBUCK, 512, 0, stream>>>(payl, zbuf, bbase, rowptr, sorted);
    k_loop<<<1024, 512, 0, stream>>>(h, loopW, delta, L);
    k_aggregate<<<2048, 512, 0, stream>>>(rowptr, sorted, hWb, relW, h, evolveW, L, delta, out);
}

// Round 8
// 289.238 us; speedup vs baseline: 2.4882x; 1.0781x over previous
//
#include <hip/hip_runtime.h>
#include <hip/hip_bf16.h>

#define N_NODES 100000
#define N_EDGES 1600000
#define D       64
#define N_RELS  200
#define LEAKY   0.01f
// fine buckets of 128 nodes; z (d&127) packed into payl.y bits 25..31
#define NBUCK      782
#define BUCK_SHIFT 7
#define BUCK_MASK  127
#define NPB        128
#define CAP        3072            // LDS record capacity; mean 2048, sigma~45 -> 22 sigma
#define BIN_CHUNK  4096
#define NBIN       ((N_EDGES + BIN_CHUNK - 1) / BIN_CHUNK)   // 391

typedef __hip_bfloat16 bf16;

__device__ __forceinline__ float b2f(bf16 x) { return __bfloat162float(x); }
__device__ __forceinline__ bf16  f2b(float x) { return __float2bfloat16(x); }

// dtype-dispatching float load: bf==1 -> storage is bf16, else f32 (probe says f32 here)
__device__ __forceinline__ float ldf(const void* p, long i, int bf) {
    return bf ? __bfloat162float(((const bf16*)p)[i]) : ((const float*)p)[i];
}
__device__ __forceinline__ int probe_bf(const void* delta) {
    return ((const unsigned short*)delta)[0] == 0x3F80 ? 1 : 0;
}

// uniform-index lane broadcast via v_readlane (result lands in SGPR)
__device__ __forceinline__ int rl_i(int v, int l) {
    return __builtin_amdgcn_readlane(v, l);
}
__device__ __forceinline__ float rl_f(float v, int l) {
    return __int_as_float(__builtin_amdgcn_readlane(__float_as_int(v), l));
}

// K1: node proj (hWb, s_src, s_dst) + rel proj (relW f32, s_rel) + coarse dst histogram.
// 8 nodes/iter (8 indep FMA chains) at (512,4): wreg[64]+hv[8]+acc[8] ~ 95 VGPR < 128 cap.
// (round-4 spill was the (512,8) 64-VGPR cap, not the 8-node structure.)
// grid 782 -> 6256 waves * 8 nodes * 2 iters = 100096: balanced, no barrier imbalance.
__global__ __launch_bounds__(512, 4) void k_fused_proj(const void* __restrict__ h,
                                                       const void* __restrict__ wn,
                                                       const void* __restrict__ attn,
                                                       const void* __restrict__ delta,
                                                       const void* __restrict__ rel_emb,
                                                       const int* __restrict__ dst,
                                                       bf16* __restrict__ hWb,
                                                       float* __restrict__ s_src,
                                                       float* __restrict__ s_dst,
                                                       float* __restrict__ relW,
                                                       float* __restrict__ s_rel,
                                                       int* __restrict__ bcnt) {
    __shared__ int bh[NBUCK];
    const int bf = probe_bf(delta);
    const int wave = threadIdx.x >> 6;
    const int lane = threadIdx.x & 63;
    const int gw = blockIdx.x * 8 + wave;
    const int nwaves = gridDim.x * 8;
    float wreg[D];
    #pragma unroll
    for (int k = 0; k < D; k++) wreg[k] = ldf(wn, (long)k * D + lane, bf);
    const float a1 = ldf(attn, lane, bf);
    const float a2 = ldf(attn, D + lane, bf);
    // phase A: 8 nodes per iteration (N_NODES % 8 == 0)
    for (int base = gw * 8; base < N_NODES; base += nwaves * 8) {
        float hv[8], acc[8];
        #pragma unroll
        for (int j = 0; j < 8; j++) {
            hv[j] = ldf(h, (long)(base + j) * D + lane, bf);
            acc[j] = 0.f;
        }
        #pragma unroll
        for (int j = 0; j < 8; j++) {
            float p1 = hv[j] * a1, p2 = hv[j] * a2;
            #pragma unroll
            for (int off = 32; off; off >>= 1) { p1 += __shfl_xor(p1, off); p2 += __shfl_xor(p2, off); }
            if (lane == 0) { s_src[base + j] = p1; s_dst[base + j] = p2; }
        }
        #pragma unroll
        for (int k = 0; k < D; k++) {
            float w = wreg[k];
            #pragma unroll
            for (int j = 0; j < 8; j++) acc[j] += rl_f(hv[j], k) * w;
        }
        #pragma unroll
        for (int j = 0; j < 8; j++) hWb[(long)(base + j) * D + lane] = f2b(acc[j]);
    }
    // phase B: relations (200 waves; L2-hot, tiny)
    const float a3 = ldf(attn, 2 * D + lane, bf);
    for (int r = gw; r < N_RELS; r += nwaves) {
        float rv = ldf(rel_emb, (long)r * D + lane, bf);
        float p3 = rv * a3;
        #pragma unroll
        for (int off = 32; off; off >>= 1) p3 += __shfl_xor(p3, off);
        if (lane == 0) s_rel[r] = p3;
        float acc = 0.f;
        #pragma unroll
        for (int k = 0; k < D; k++) {
            acc += rl_f(rv, k) * ldf(wn, (long)(D + k) * D + lane, bf);
        }
        relW[r * D + lane] = acc;
    }
    // phase C: coarse (dst>>7) histogram, LDS-aggregated
    for (int t = threadIdx.x; t < NBUCK; t += 512) bh[t] = 0;
    __syncthreads();
    for (int t = blockIdx.x * 512 + threadIdx.x; t < N_EDGES; t += gridDim.x * 512)
        atomicAdd(&bh[dst[t] >> BUCK_SHIFT], 1);
    __syncthreads();
    for (int t = threadIdx.x; t < NBUCK; t += 512) {
        int v = bh[t];
        if (v) atomicAdd(&bcnt[t], v);
    }
}

// exclusive scan of the 782 bucket counts; primes bcursor and bbase
__global__ __launch_bounds__(1024) void k_bscan(const int* __restrict__ bcnt,
                                                int* __restrict__ bbase,
                                                int* __restrict__ bcursor) {
    __shared__ int s[1024];
    const int tid = threadIdx.x;
    int v = (tid < NBUCK) ? bcnt[tid] : 0;
    s[tid] = v;
    __syncthreads();
    for (int off = 1; off < 1024; off <<= 1) {
        int t = (tid >= off) ? s[tid - off] : 0;
        __syncthreads();
        s[tid] += t;
        __syncthreads();
    }
    if (tid < NBUCK) {
        int e = s[tid] - v;
        bbase[tid] = e;
        bcursor[tid] = e;
    }
    if (tid == 1023) bbase[NBUCK] = s[1023];   // == N_EDGES
}

// Pass B: rank edges into 782 fine buckets via LDS atomics, then scatter
// {ex, src | rel<<17 | z<<25} (8B) into per-(block,bucket) runs (~5 recs / ~42B).
// No zbuf: z packed in payl.y. 3 barriers, ~6.3 KB LDS.
__global__ __launch_bounds__(512, 4) void k_bin(const float* __restrict__ s_src,
                                                const float* __restrict__ s_dst,
                                                const float* __restrict__ s_rel,
                                                const void* __restrict__ etime,
                                                const void* __restrict__ delta,
                                                const int* __restrict__ src,
                                                const int* __restrict__ dst,
                                                const int* __restrict__ etype,
                                                int* __restrict__ bcursor,
                                                int2* __restrict__ payl) {
    __shared__ int lh[NBUCK];
    __shared__ int gbase[NBUCK];
    const int bf = probe_bf(delta);
    const float df = ldf(delta, 0, bf);
    const int tid = threadIdx.x;
    const int base = blockIdx.x * BIN_CHUNK;
    for (int t = tid; t < NBUCK; t += 512) lh[t] = 0;
    __syncthreads();
    int2 rc[8];
    int rk[8], bk[8];
    #pragma unroll
    for (int j = 0; j < 8; j++) {
        int e = base + j * 512 + tid;
        bk[j] = -1;
        if (e < N_EDGES) {
            int s = src[e], d = dst[e], r = etype[e];
            float scv = s_src[s] + s_dst[d] + s_rel[r];
            float lre = scv > 0.f ? scv : LEAKY * scv;
            float score = (-ldf(etime, e, bf) * df) * lre;
            rc[j].x = __float_as_int(__expf(score));
            rc[j].y = s | (r << 17) | ((d & BUCK_MASK) << 25);  // 17+8+7 = 32 bits
            int b = d >> BUCK_SHIFT;
            bk[j] = b;
            rk[j] = atomicAdd(&lh[b], 1);
        }
    }
    __syncthreads();
    for (int t = tid; t < NBUCK; t += 512) {
        int v = lh[t];
        if (v) gbase[t] = atomicAdd(&bcursor[t], v);
    }
    __syncthreads();
    #pragma unroll
    for (int j = 0; j < 8; j++) {
        if (bk[j] >= 0) payl[gbase[bk[j]] + rk[j]] = rc[j];
    }
}

// Dense loop-term: L[i] = h[i] @ loopW for ALL nodes. 8 nodes/iter at (512,4),
// grid 782 (balanced). deg==0 nodes (P=e^-16) corrected in k_bagg's cold branch.
__global__ __launch_bounds__(512, 4) void k_loop(const void* __restrict__ h,
                                                 const void* __restrict__ loopW,
                                                 const void* __restrict__ delta,
                                                 float* __restrict__ L) {
    const int bf = probe_bf(delta);
    const int wave = threadIdx.x >> 6;
    const int lane = threadIdx.x & 63;
    const int gw = blockIdx.x * 8 + wave;
    const int nwaves = gridDim.x * 8;
    float wreg[D];
    #pragma unroll
    for (int k = 0; k < D; k++) wreg[k] = ldf(loopW, (long)k * D + lane, bf);
    for (int base = gw * 8; base < N_NODES; base += nwaves * 8) {
        float hv[8], acc[8];
        #pragma unroll
        for (int j = 0; j < 8; j++) {
            hv[j] = ldf(h, (long)(base + j) * D + lane, bf);
            acc[j] = 0.f;
        }
        #pragma unroll
        for (int k = 0; k < D; k++) {
            float w = wreg[k];
            #pragma unroll
            for (int j = 0; j < 8; j++) acc[j] += rl_f(hv[j], k) * w;
        }
        #pragma unroll
        for (int j = 0; j < 8; j++) L[(long)(base + j) * D + lane] = acc[j];
    }
}

// Fused bucket-sort + aggregate: one block per 128-node bucket. Sort the bucket's
// edge run into LDS (no global `sorted`, no rowptr), then aggregate directly from
// LDS with group-broadcast reads (no per-edge shfl). Node z's records occupy
// [off[z], off[z]+cnt[z]) deterministically; if that range exceeds CAP (>=22 sigma,
// ~never) the node is recomputed by a z-filtered global rescan of the run.
__global__ __launch_bounds__(512, 4) void k_bagg(const int2* __restrict__ payl,
                                                 const int* __restrict__ bbase,
                                                 const bf16* __restrict__ hWb,
                                                 const float* __restrict__ relW,
                                                 const void* __restrict__ h,
                                                 const void* __restrict__ evolveW,
                                                 const float* __restrict__ L,
                                                 const void* __restrict__ delta,
                                                 float* __restrict__ out) {
    __shared__ int2 recs[CAP];              // 24 KB
    __shared__ int cnt[NPB], off[NPB], fc[NPB];
    const int bf = probe_bf(delta);
    const int tid = threadIdx.x;
    const int b = blockIdx.x;
    const int n0 = b << BUCK_SHIFT;
    const int s0 = bbase[b], s1 = bbase[b + 1];
    const int run = s1 - s0;
    if (tid < NPB) { cnt[tid] = 0; fc[tid] = 0; }
    __syncthreads();
    // fine histogram over the run
    for (int i = tid; i < run; i += 512)
        atomicAdd(&cnt[((unsigned)payl[s0 + i].y) >> 25], 1);
    __syncthreads();
    if (tid < NPB) off[tid] = cnt[tid];
    __syncthreads();
    for (int o = 1; o < NPB; o <<= 1) {
        int t = 0;
        if (tid < NPB && tid >= o) t = off[tid - o];
        __syncthreads();
        if (tid < NPB) off[tid] += t;
        __syncthreads();
    }
    if (tid < NPB) off[tid] -= cnt[tid];    // exclusive offsets
    __syncthreads();
    // scatter into LDS (payl re-read is L2-hot)
    for (int i = tid; i < run; i += 512) {
        int2 r = payl[s0 + i];
        int z = ((unsigned)r.y) >> 25;
        int pos = off[z] + atomicAdd(&fc[z], 1);
        if (pos < CAP) recs[pos] = r;
    }
    __syncthreads();
    // aggregation: 8 waves x 16 nodes, 4-group x 16-lane x 4-channel gather
    const int wave = tid >> 6, lane = tid & 63;
    const int grp = lane >> 4, sub = lane & 15;
    const unsigned sub8 = (unsigned)sub << 3;
    const unsigned sub16 = (unsigned)sub << 4;
    for (int t = 0; t < 16; ++t) {
        const int z = wave * 16 + t;
        const int i = n0 + z;
        if (i >= N_NODES) break;
        const int d = cnt[z], o = off[z];
        if (d > 0) {
            float ax = 0.f, ay = 0.f, az = 0.f, aw = 0.f, ws = 0.f;
            if (o + d <= CAP) {
                #pragma unroll 2
                for (int j = 0; j < d; j += 4) {
                    int jj = j + grp;
                    int2 rr = (jj < d) ? recs[o + jj] : make_int2(0, 0);  // LDS broadcast in group
                    float w = __int_as_float(rr.x);                        // 0.0 when masked
                    int p = rr.y;
                    unsigned hoff = ((unsigned)(p & 0x1FFFF) << 7) + sub8;
                    unsigned roff = ((((unsigned)p >> 17) & 0xFFu) << 8) + sub16;
                    uint2  hw = *(const uint2*) ((const char*)hWb  + hoff);
                    float4 rw = *(const float4*)((const char*)relW + roff);
                    float f0 = __uint_as_float(hw.x << 16);
                    float f1 = __uint_as_float(hw.x & 0xFFFF0000u);
                    float f2 = __uint_as_float(hw.y << 16);
                    float f3 = __uint_as_float(hw.y & 0xFFFF0000u);
                    ax += w * (f0 + rw.x);
                    ay += w * (f1 + rw.y);
                    az += w * (f2 + rw.z);
                    aw += w * (f3 + rw.w);
                    ws += w;
                }
            } else {
                // ~never taken: z-filtered rescan of the global run, same fold shape
                for (int j = 0; j < run; j += 4) {
                    int jj = j + grp;
                    if (jj < run) {
                        int2 rr = payl[s0 + jj];
                        if ((int)(((unsigned)rr.y) >> 25) == z) {
                            float w = __int_as_float(rr.x);
                            int p = rr.y;
                            unsigned hoff = ((unsigned)(p & 0x1FFFF) << 7) + sub8;
                            unsigned roff = ((((unsigned)p >> 17) & 0xFFu) << 8) + sub16;
                            uint2  hw = *(const uint2*) ((const char*)hWb  + hoff);
                            float4 rw = *(const float4*)((const char*)relW + roff);
                            ax += w * (__uint_as_float(hw.x << 16) + rw.x);
                            ay += w * (__uint_as_float(hw.x & 0xFFFF0000u) + rw.y);
                            az += w * (__uint_as_float(hw.y << 16) + rw.z);
                            aw += w * (__uint_as_float(hw.y & 0xFFFF0000u) + rw.w);
                            ws += w;
                        }
                    }
                }
            }
            // fold the 4 group-partials (group-uniform ws folds identically)
            ax += __shfl_xor(ax, 16); ax += __shfl_xor(ax, 32);
            ay += __shfl_xor(ay, 16); ay += __shfl_xor(ay, 32);
            az += __shfl_xor(az, 16); az += __shfl_xor(az, 32);
            aw += __shfl_xor(aw, 16); aw += __shfl_xor(aw, 32);
            ws += __shfl_xor(ws, 16); ws += __shfl_xor(ws, 32);
            if (grp == 0) {
                const float inv = 1.f / ws;     // ws > 0: every stored ex = exp(finite) > 0
                const float4 l4 = *(const float4*)(L + (long)i * D + sub * 4);
                float4 r;
                r.x = ax * inv + l4.x;
                r.y = ay * inv + l4.y;
                r.z = az * inv + l4.z;
                r.w = aw * inv + l4.w;
                *(float4*)(out + (long)i * D + sub * 4) = r;
            }
        } else {
            // cold: deg==0 (P=e^-16). out = h + h @ evolveW; evolveW is L2-hot.
            float hv = ldf(h, (long)i * D + lane, bf);
            float acc = hv;
            for (int k = 0; k < D; k++)
                acc += rl_f(hv, k) * ldf(evolveW, (long)k * D + lane, bf);
            out[(long)i * D + lane] = acc;
        }
    }
}

// safe diagnostic fallback
__global__ __launch_bounds__(256) void k_fallback(float* __restrict__ out) {
    int t = blockIdx.x * blockDim.x + threadIdx.x;
    if (t < N_NODES * D) out[t] = 0.f;
}

extern "C" void kernel_launch(void* const* d_in, const int* in_sizes, int n_in,
                              void* d_out, int out_size, void* d_ws, size_t ws_size,
                              hipStream_t stream) {
    const void* h       = d_in[0];
    const void* rel_emb = d_in[1];
    const void* wn      = d_in[2];
    const void* attn    = d_in[3];
    const void* delta   = d_in[4];
    const void* loopW   = d_in[5];
    const void* evolveW = d_in[6];
    const void* etime   = d_in[7];
    const int*  src     = (const int*)d_in[8];
    const int*  dst     = (const int*)d_in[9];
    const int*  etype   = (const int*)d_in[10];
    float* out = (float*)d_out;

    char* ws = (char*)d_ws;
    size_t off = 0;
    auto alloc = [&](size_t bytes) -> void* {
        off = (off + 255) & ~(size_t)255;
        void* p = ws + off;
        off += bytes;
        return p;
    };
    int2*  payl    = (int2*) alloc((size_t)N_EDGES * 8);       // 12.8 MB
    float* L       = (float*)alloc((size_t)N_NODES * D * 4);   // 25.6 MB
    bf16*  hWb     = (bf16*) alloc((size_t)N_NODES * D * 2);   // 12.8 MB
    float* relW    = (float*)alloc((size_t)N_RELS * D * 4);    // 51.2 KB
    float* s_src   = (float*)alloc((size_t)N_NODES * 4);       //  0.4 MB
    float* s_dst   = (float*)alloc((size_t)N_NODES * 4);       //  0.4 MB
    float* s_rel   = (float*)alloc((size_t)N_RELS * 4);        //  0.8 KB
    int*   bcnt    = (int*)  alloc((size_t)NBUCK * 4);
    int*   bbase   = (int*)  alloc((size_t)(NBUCK + 1) * 4);
    int*   bcursor = (int*)  alloc((size_t)NBUCK * 4);
    // total ~52.1 MB (< proven-available 52.9 MB from rounds 1-7)

    if (ws_size < off) {
        k_fallback<<<(N_NODES * D + 255) / 256, 256, 0, stream>>>(out);
        return;
    }

    hipMemsetAsync(bcnt, 0, (size_t)NBUCK * 4, stream);
    k_fused_proj<<<782, 512, 0, stream>>>(h, wn, attn, delta, rel_emb, dst,
                                          hWb, s_src, s_dst, relW, s_rel, bcnt);
    k_bscan<<<1, 1024, 0, stream>>>(bcnt, bbase, bcursor);
    k_bin<<<NBIN, 512, 0, stream>>>(s_src, s_dst, s_rel, etime, delta,
                                    src, dst, etype, bcursor, payl);
    k_loop<<<782, 512, 0, stream>>>(h, loopW, delta, L);
    k_bagg<<<NBUCK, 512, 0, stream>>>(payl, bbase, hWb, relW, h, evolveW, L, delta, out);
}